// Round 7
// baseline (155.984 us; speedup 1.0000x reference)
//
#include <hip/hip_runtime.h>

#define IS 256
#define NEARV 0.1f
#define FARV 100.0f
#define NTX 16                    // 16x16 tiles of 16x16 px
#define NTILES 256
#define CAP 5120                  // per-tile list capacity >= nf -> overflow impossible
#define CHK 32                    // entries per raster chunk (r5: CHK=16 regresses)
#define CPT (CAP / CHK)           // 160 chunk slots per tile
#define RBLOCKS 2048              // 8192 waves = 256 tiles x 32 chunk-lanes
#define RWAVES (RBLOCKS * 4)

// ---------------- kernel 1: init ----------------
// zb (d_out; raw float bits, atomicMin'd; positive floats compare as uints)
// init to 100.0f = FAR; zero tile counts. (No ticket/misc: the item-list
// machinery is gone entirely -- see kraster's closed-form work mapping.)
__global__ void kinit(unsigned int* __restrict__ zb, int* __restrict__ count) {
    int i = blockIdx.x * 256 + threadIdx.x;
    zb[i] = 0x42C80000u;  // __float_as_uint(100.0f); grid == IS*IS exactly
    if (i < NTILES) count[i] = 0;
}

// ---------------- kernel 2: prep + bin (r3 verbatim, epilogue DELETED) ----------------
// r5 counters: this stage ran 40.6us at 0.7% VALUBusy -- a near-idle machine
// paying latency, with the serial last-block epilogue (ticket + fences + 16-
// barrier scan + item emission) on ONE block while 255 CUs idle. The fix is
// structural: no epilogue at all. Kernel ends after pass B; raster derives
// its work from count[] alone.
// Per thread: gather+transform+cull its face in registers (arithmetic
// expression-identical to all verified rounds), write the 48B raster record,
// bin via two-level LDS counting (one global atomicAdd per (block,tile)
// nonzero -> contiguous per-tile lists).
__launch_bounds__(256)
__global__ void kbinprep(const float* __restrict__ verts, const int* __restrict__ faces,
                         float4* __restrict__ fd, int* __restrict__ count,
                         unsigned short* __restrict__ list, int nf) {
    __shared__ int scnt[NTILES];
    __shared__ int sbase[NTILES];
    const int tid = threadIdx.x;
    for (int t = tid; t < NTILES; t += 256) scnt[t] = 0;
    __syncthreads();

    const int f = blockIdx.x * 256 + tid;
    int kx0 = 0, kx1 = -1, ky0 = 0, ky1 = -1;     // empty range for dead faces
    float bxmin = 0.f, bymin = 0.f, bxmax = -1.f, bymax = -1.f;
    if (f < nf) {
        int i0 = faces[f * 3 + 0];
        int i1 = faces[f * 3 + 1];
        int i2 = faces[f * 3 + 2];
        // transform (v - eye; R == I exactly in fp32 for this camera)
        float z0 = verts[i0 * 3 + 2] + 2.7320508075688772f;
        float z1 = verts[i1 * 3 + 2] + 2.7320508075688772f;
        float z2 = verts[i2 * 3 + 2] + 2.7320508075688772f;
        bool front = (z0 > NEARV) && (z1 > NEARV) && (z2 > NEARV);
        float zs0 = (fabsf(z0) < 1e-5f) ? 1e-5f : z0;
        float zs1 = (fabsf(z1) < 1e-5f) ? 1e-5f : z1;
        float zs2 = (fabsf(z2) < 1e-5f) ? 1e-5f : z2;
        float d0 = zs0 * 0.57735026918962576f;  // zs * tan(30 deg)
        float d1 = zs1 * 0.57735026918962576f;
        float d2 = zs2 * 0.57735026918962576f;
        float x0 = verts[i0 * 3 + 0] / d0;
        float y0 = verts[i0 * 3 + 1] / d0;
        float x1 = verts[i1 * 3 + 0] / d1;
        float y1 = verts[i1 * 3 + 1] / d1;
        float x2 = verts[i2 * 3 + 0] / d2;
        float y2 = verts[i2 * 3 + 1] / d2;
        float area = (x1 - x0) * (y2 - y0) - (x2 - x0) * (y1 - y0);
        if (front && (fabsf(area) > 1e-8f)) {
            bxmin = fminf(x0, fminf(x1, x2));
            bxmax = fmaxf(x0, fmaxf(x1, x2));
            bymin = fminf(y0, fminf(y1, y2));
            bymax = fmaxf(y0, fmaxf(y1, y2));
            float ia = 1.0f / area;  // |area| > 1e-8 so area_s == area
            float iz0 = 1.0f / fmaxf(z0, 1e-4f);
            float iz1 = 1.0f / fmaxf(z1, 1e-4f);
            float iz2 = 1.0f / fmaxf(z2, 1e-4f);
            float4* o = fd + (size_t)f * 4;
            o[0] = make_float4(x0, y0, x1, y1);
            o[1] = make_float4(x2, y2, ia, iz0);
            o[2] = make_float4(iz1, iz2, 0.0f, 0.0f);
            // conservative k-range (+/-1), exact predicate re-tested below
            float tminx = fminf(fmaxf((bxmin * 256.0f + 225.0f) * (1.0f / 32.0f), -2.0f), 17.0f);
            float tmaxx = fminf(fmaxf((bxmax * 256.0f + 255.0f) * (1.0f / 32.0f), -2.0f), 17.0f);
            float tminy = fminf(fmaxf((bymin * 256.0f + 225.0f) * (1.0f / 32.0f), -2.0f), 17.0f);
            float tmaxy = fminf(fmaxf((bymax * 256.0f + 255.0f) * (1.0f / 32.0f), -2.0f), 17.0f);
            kx0 = max(0, (int)ceilf(tminx) - 1);
            kx1 = min(NTX - 1, (int)floorf(tmaxx) + 1);
            ky0 = max(0, (int)ceilf(tminy) - 1);
            ky1 = min(NTX - 1, (int)floorf(tmaxy) + 1);
        }
    }
    // pass A: count (exact dyadic tile-overlap predicate -> bit-identical sets)
    for (int ky = ky0; ky <= ky1; ++ky) {
        float py_lo = (float)(32 * ky - 255) * (1.0f / 256.0f);
        float py_hi = (float)(32 * ky - 225) * (1.0f / 256.0f);
        if (!(bymin <= py_hi && bymax >= py_lo)) continue;
        for (int kx = kx0; kx <= kx1; ++kx) {
            float px_lo = (float)(32 * kx - 255) * (1.0f / 256.0f);
            float px_hi = (float)(32 * kx - 225) * (1.0f / 256.0f);
            if (bxmin <= px_hi && bxmax >= px_lo) atomicAdd(&scnt[ky * NTX + kx], 1);
        }
    }
    __syncthreads();
    for (int t = tid; t < NTILES; t += 256) {
        int c = scnt[t];
        sbase[t] = (c > 0) ? atomicAdd(&count[t], c) : 0;
        scnt[t] = 0;  // reuse as per-block cursor
    }
    __syncthreads();
    // pass B: scatter (order within a tile list irrelevant: min is commutative)
    for (int ky = ky0; ky <= ky1; ++ky) {
        float py_lo = (float)(32 * ky - 255) * (1.0f / 256.0f);
        float py_hi = (float)(32 * ky - 225) * (1.0f / 256.0f);
        if (!(bymin <= py_hi && bymax >= py_lo)) continue;
        for (int kx = kx0; kx <= kx1; ++kx) {
            float px_lo = (float)(32 * kx - 255) * (1.0f / 256.0f);
            float px_hi = (float)(32 * kx - 225) * (1.0f / 256.0f);
            if (bxmin <= px_hi && bxmax >= px_lo) {
                int t = ky * NTX + kx;
                int slot = sbase[t] + atomicAdd(&scnt[t], 1);
                list[(size_t)t * CAP + slot] = (unsigned short)f;
            }
        }
    }
    // (no epilogue -- kernel ends; stream order publishes fd/list/count)
}

// ---------------- kernel 3: raster (closed-form work mapping) ----------------
// 8192 waves = 256 tiles x 32 chunk-lanes. Wave wid owns tile = wid & 255 and
// chunks k in {wid>>8, +32, +64, ...} of that tile's CONTIGUOUS list. A hot
// tile (count ~1500 -> ~47 chunks) spreads across its 32 waves at <=2 chunks
// each; cold tiles cost one wave-uniform scalar count load. No items array,
// no nitems, no ticket/scan anywhere in the pipeline.
// All of a wave's chunks hit the SAME 256 pixels -> mx accumulates across
// chunks and the atomicMin epilogue runs ONCE per wave.
// Inner loop = verbatim round-3 batch-staged LDS broadcast: lanes 0..n-1 load
// one entry index (coalesced ushort) + 48B face record (3x dwordx4, ONE vmcnt
// batch per chunk), stage to wave-private LDS, entry loop reads via same-
// address ds_read_b128 (broadcast, conflict-free). Wave-internal s_waitcnt
// lgkmcnt(0) orders write->read (DS pipe is in-order per wave, so read-then-
// overwrite across k iterations is safe; no block barrier -- trip counts
// differ). Pixel math expression-identical to all verified rounds; min3
// predicate is an exact reformulation of the three sign tests. zb pre-read
// once per wave; atomicMin only when it would win (zb monotone-decreasing ->
// stale read conservatively safe).
__launch_bounds__(256)
__global__ void kraster(const float4* __restrict__ fd, const unsigned short* __restrict__ list,
                        const int* __restrict__ count, unsigned int* __restrict__ zb) {
    __shared__ float4 sdata[4][CHK * 3];   // 6 KB: [wave][entry*3 + part]
    const int wslot = __builtin_amdgcn_readfirstlane(threadIdx.x >> 6);
    const int wid = blockIdx.x * 4 + wslot;
    const int lane = threadIdx.x & 63;
    const int cx = lane & 15;
    const int ry = lane >> 4;
    float4* sd = &sdata[wslot][0];

    const int tile = wid & 255;
    const int cc = wid >> 8;                         // chunk-lane 0..31
    const int c = count[tile];                       // wave-uniform scalar load
    const int nch = (c + CHK - 1) / CHK;
    if (cc >= nch) return;

    const int bx = tile & 15;
    const int by = tile >> 4;
    const int j = bx * 16 + cx;
    const float px = ((float)(2 * j + 1) - 256.0f) * (1.0f / 256.0f);
    float py[4];
    int row[4];
    unsigned int zcur[4];
#pragma unroll
    for (int r = 0; r < 4; ++r) {
        row[r] = by * 16 + ry + 4 * r;
        py[r] = ((float)(2 * row[r] + 1) - 256.0f) * (1.0f / 256.0f);
        zcur[r] = zb[row[r] * IS + j];
    }

    float mx[4] = {0.0f, 0.0f, 0.0f, 0.0f};

    for (int k = cc; k < nch; k += 32) {             // <=2 iterations for hot tiles
        const int n = min(CHK, c - k * CHK);         // >=1 by k < nch
        // ---- stage this chunk's face records into wave-private LDS ----
        const unsigned short* lp = list + (size_t)tile * CAP + k * CHK;
        if (lane < n) {
            const int fidx = lp[lane];                 // coalesced 2B/lane
            const float4* p = fd + (size_t)fidx * 4;   // 3 dwordx4, batched vmcnt
            float4 b0 = p[0];
            float4 b1 = p[1];
            float4 b2 = p[2];
            sd[lane * 3 + 0] = b0;
            sd[lane * 3 + 1] = b1;
            sd[lane * 3 + 2] = b2;
        }
        // wave-internal write->read ordering (no block barrier)
        asm volatile("s_waitcnt lgkmcnt(0)" ::: "memory");

#pragma unroll 2
        for (int e = 0; e < n; ++e) {
            float4 a0 = sd[e * 3 + 0];   // uniform addr -> LDS broadcast
            float4 a1 = sd[e * 3 + 1];
            float4 a2 = sd[e * 3 + 2];
            float dx0 = a0.x - px, dx1 = a0.z - px, dx2 = a1.x - px;
#pragma unroll
            for (int r = 0; r < 4; ++r) {
                float dy0 = a0.y - py[r], dy1 = a0.w - py[r], dy2 = a1.y - py[r];
                float e0 = dx1 * dy2 - dx2 * dy1;
                float e1 = dx2 * dy0 - dx0 * dy2;
                float w0 = e0 * a1.z;
                float w1 = e1 * a1.z;
                float w2 = 1.0f - w0 - w1;
                float invz = w0 * a1.w + w1 * a2.x + w2 * a2.y;
                float invzc = fmaxf(invz, 1e-6f);
                // all(w>=0) <=> min3(w0,w1,w2)>=0 (exact; mult by positive ia
                // preserves sign). valid NEAR<zp<FAR <=> 0.01 < invzc < 10.
                float wmin = fminf(fminf(w0, w1), w2);
                bool ok = (wmin >= 0.0f) && (invzc < 10.0f) && (invzc > 0.01f);
                if (ok) mx[r] = fmaxf(mx[r], invzc);
            }
        }
    }
#pragma unroll
    for (int r = 0; r < 4; ++r) {
        if (mx[r] > 0.0f) {
            float zp = 1.0f / mx[r];  // correctly-rounded 1/x monotone => min-exact
            unsigned int zbits = __float_as_uint(zp);
            if (zbits < zcur[r]) atomicMin(&zb[row[r] * IS + j], zbits);
        }
    }
}

extern "C" void kernel_launch(void* const* d_in, const int* in_sizes, int n_in,
                              void* d_out, int out_size, void* d_ws, size_t ws_size,
                              hipStream_t stream) {
    const float* verts = (const float*)d_in[0];
    const int* faces = (const int*)d_in[1];
    unsigned int* zb = (unsigned int*)d_out;  // float bits, min'd in place

    const int nf = in_sizes[1] / 3;  // 5000 (< CAP and < 65536: ushort indices ok)

    char* ws = (char*)d_ws;
    size_t off = 0;
    float4* fd = (float4*)(ws + off);            off += (size_t)nf * 64;   // 320 KB
    off = (off + 255) & ~(size_t)255;
    int* count = (int*)(ws + off);               off += NTILES * 4;        // 1 KB
    off = (off + 255) & ~(size_t)255;
    unsigned short* list = (unsigned short*)(ws + off);  // 256*5120*2 = 2.62 MB

    const int nb = (nf + 255) / 256;  // 20 blocks

    kinit<<<(IS * IS) / 256, 256, 0, stream>>>(zb, count);
    kbinprep<<<nb, 256, 0, stream>>>(verts, faces, fd, count, list, nf);
    kraster<<<RBLOCKS, 256, 0, stream>>>(fd, list, count, zb);
}

// Round 8
// 115.330 us; speedup vs baseline: 1.3525x; 1.3525x over previous
//
#include <hip/hip_runtime.h>

#define IS 256
#define NEARV 0.1f
#define FARV 100.0f
#define NTX 16                    // 16x16 tiles of 16x16 px
#define NTILES 256
#define CAP 5120                  // per-tile list capacity >= nf -> overflow impossible
#define CHK 32                    // entries per raster work item (r5: CHK=16 regresses)
#define CPT ((CAP + CHK - 1) / CHK)   // max chunks per tile = 160 (fits 8-bit field: <256)
#define RBLOCKS 2048
#define RWAVES (RBLOCKS * 4)
#define MAXITEMS (NTILES * CPT)
#define BTH 1024                  // binning block size: 16 waves/block = 4 waves/SIMD

// ---------------- kernel 1: fused init + prep + bin + items ----------------
// r5/r7 diagnosis: 256-thread binning blocks give 1 wave/SIMD on the active
// CUs -> every gather/LDS-atomic/barrier latency fully exposed (40.6us at
// 0.7% VALUBusy). Fix: 1024-thread blocks (5 blocks) = 4 waves/SIMD on each
// active CU. zb init is folded in as coalesced uint4 stores (independent
// work that also hides the transform's dependent-load latency). count+misc
// are zeroed by a hipMemsetAsync before this kernel (stream-ordered DMA, no
// kernel-launch ramp; the harness itself uses hipMemsetAsync under capture).
// All face arithmetic, binning passes, ticket+scan epilogue and item packing
// are VERBATIM the round-3 code (benched 107.8, absmax 0.0).
__launch_bounds__(BTH)
__global__ void kbinprep(const float* __restrict__ verts, const int* __restrict__ faces,
                         float4* __restrict__ fd, int* __restrict__ count,
                         unsigned short* __restrict__ list, int* __restrict__ misc,
                         int* __restrict__ items, unsigned int* __restrict__ zb, int nf) {
    __shared__ int scnt[NTILES];
    __shared__ int sbase[NTILES];
    __shared__ int slast;
    const int tid = threadIdx.x;
    const int gid = blockIdx.x * BTH + tid;
    const int nthr = gridDim.x * BTH;

    // zb init: 16384 uint4 = 256KB of FAR bits, coalesced, grid-strided
    {
        uint4* zb4 = (uint4*)zb;
        const uint4 farv = make_uint4(0x42C80000u, 0x42C80000u, 0x42C80000u, 0x42C80000u);
        for (int i = gid; i < (IS * IS) / 4; i += nthr) zb4[i] = farv;
    }

    if (tid < NTILES) scnt[tid] = 0;
    __syncthreads();

    const int f = gid;
    int kx0 = 0, kx1 = -1, ky0 = 0, ky1 = -1;     // empty range for dead faces
    float bxmin = 0.f, bymin = 0.f, bxmax = -1.f, bymax = -1.f;
    if (f < nf) {
        int i0 = faces[f * 3 + 0];
        int i1 = faces[f * 3 + 1];
        int i2 = faces[f * 3 + 2];
        // transform (v - eye; R == I exactly in fp32 for this camera)
        float z0 = verts[i0 * 3 + 2] + 2.7320508075688772f;
        float z1 = verts[i1 * 3 + 2] + 2.7320508075688772f;
        float z2 = verts[i2 * 3 + 2] + 2.7320508075688772f;
        bool front = (z0 > NEARV) && (z1 > NEARV) && (z2 > NEARV);
        float zs0 = (fabsf(z0) < 1e-5f) ? 1e-5f : z0;
        float zs1 = (fabsf(z1) < 1e-5f) ? 1e-5f : z1;
        float zs2 = (fabsf(z2) < 1e-5f) ? 1e-5f : z2;
        float d0 = zs0 * 0.57735026918962576f;  // zs * tan(30 deg)
        float d1 = zs1 * 0.57735026918962576f;
        float d2 = zs2 * 0.57735026918962576f;
        float x0 = verts[i0 * 3 + 0] / d0;
        float y0 = verts[i0 * 3 + 1] / d0;
        float x1 = verts[i1 * 3 + 0] / d1;
        float y1 = verts[i1 * 3 + 1] / d1;
        float x2 = verts[i2 * 3 + 0] / d2;
        float y2 = verts[i2 * 3 + 1] / d2;
        float area = (x1 - x0) * (y2 - y0) - (x2 - x0) * (y1 - y0);
        if (front && (fabsf(area) > 1e-8f)) {
            bxmin = fminf(x0, fminf(x1, x2));
            bxmax = fmaxf(x0, fmaxf(x1, x2));
            bymin = fminf(y0, fminf(y1, y2));
            bymax = fmaxf(y0, fmaxf(y1, y2));
            float ia = 1.0f / area;  // |area| > 1e-8 so area_s == area
            float iz0 = 1.0f / fmaxf(z0, 1e-4f);
            float iz1 = 1.0f / fmaxf(z1, 1e-4f);
            float iz2 = 1.0f / fmaxf(z2, 1e-4f);
            float4* o = fd + (size_t)f * 4;
            o[0] = make_float4(x0, y0, x1, y1);
            o[1] = make_float4(x2, y2, ia, iz0);
            o[2] = make_float4(iz1, iz2, 0.0f, 0.0f);
            // conservative k-range (+/-1), exact predicate re-tested below
            float tminx = fminf(fmaxf((bxmin * 256.0f + 225.0f) * (1.0f / 32.0f), -2.0f), 17.0f);
            float tmaxx = fminf(fmaxf((bxmax * 256.0f + 255.0f) * (1.0f / 32.0f), -2.0f), 17.0f);
            float tminy = fminf(fmaxf((bymin * 256.0f + 225.0f) * (1.0f / 32.0f), -2.0f), 17.0f);
            float tmaxy = fminf(fmaxf((bymax * 256.0f + 255.0f) * (1.0f / 32.0f), -2.0f), 17.0f);
            kx0 = max(0, (int)ceilf(tminx) - 1);
            kx1 = min(NTX - 1, (int)floorf(tmaxx) + 1);
            ky0 = max(0, (int)ceilf(tminy) - 1);
            ky1 = min(NTX - 1, (int)floorf(tmaxy) + 1);
        }
    }
    // pass A: count (exact dyadic tile-overlap predicate -> bit-identical sets)
    for (int ky = ky0; ky <= ky1; ++ky) {
        float py_lo = (float)(32 * ky - 255) * (1.0f / 256.0f);
        float py_hi = (float)(32 * ky - 225) * (1.0f / 256.0f);
        if (!(bymin <= py_hi && bymax >= py_lo)) continue;
        for (int kx = kx0; kx <= kx1; ++kx) {
            float px_lo = (float)(32 * kx - 255) * (1.0f / 256.0f);
            float px_hi = (float)(32 * kx - 225) * (1.0f / 256.0f);
            if (bxmin <= px_hi && bxmax >= px_lo) atomicAdd(&scnt[ky * NTX + kx], 1);
        }
    }
    __syncthreads();
    if (tid < NTILES) {
        int c = scnt[tid];
        sbase[tid] = (c > 0) ? atomicAdd(&count[tid], c) : 0;
        scnt[tid] = 0;  // reuse as per-block cursor
    }
    __syncthreads();
    // pass B: scatter (order within a tile list irrelevant: min is commutative)
    for (int ky = ky0; ky <= ky1; ++ky) {
        float py_lo = (float)(32 * ky - 255) * (1.0f / 256.0f);
        float py_hi = (float)(32 * ky - 225) * (1.0f / 256.0f);
        if (!(bymin <= py_hi && bymax >= py_lo)) continue;
        for (int kx = kx0; kx <= kx1; ++kx) {
            float px_lo = (float)(32 * kx - 255) * (1.0f / 256.0f);
            float px_hi = (float)(32 * kx - 225) * (1.0f / 256.0f);
            if (bxmin <= px_hi && bxmax >= px_lo) {
                int t = ky * NTX + kx;
                int slot = sbase[t] + atomicAdd(&scnt[t], 1);
                list[(size_t)t * CAP + slot] = (unsigned short)f;
            }
        }
    }
    // ---- last-block epilogue: build item list (needs only final count[]) ----
    __syncthreads();
    __threadfence();  // release: our count[] atomicAdds before the ticket RMW
    if (tid == 0) slast = (atomicAdd(&misc[0], 1) == (int)gridDim.x - 1) ? 1 : 0;
    __syncthreads();
    if (!slast) return;
    __threadfence();  // acquire: see every block's count[] updates
    int c = 0, nch = 0;
    if (tid < NTILES) {
        c = __hip_atomic_load(&count[tid], __ATOMIC_RELAXED, __HIP_MEMORY_SCOPE_AGENT);
        nch = (c + CHK - 1) / CHK;
        scnt[tid] = nch;
    }
    __syncthreads();
    // Hillis-Steele inclusive scan over 256 tiles (barriers hit by all waves)
    for (int d = 1; d < NTILES; d <<= 1) {
        int v = (tid >= d && tid < NTILES) ? scnt[tid - d] : 0;
        __syncthreads();
        if (tid < NTILES) scnt[tid] += v;
        __syncthreads();
    }
    if (tid < NTILES) {
        int off = scnt[tid] - nch;
        if (tid == NTILES - 1) misc[64] = scnt[tid];  // nitems
        for (int k = 0; k < nch; ++k) {
            int n = min(CHK, c - k * CHK);
            items[off + k] = (tid << 16) | (n << 8) | k;   // chunk <= 159 fits 8 bits
        }
    }
}

// ---------------- kernel 2: raster (r3 verbatim -- benched 107.8, absmax 0.0) ----------------
// One wave per item (ni ~ 2600 < RWAVES -> at most ONE chunk per wave, perfect
// static balance; r4/r7 proved serial multi-chunk waves are the failure mode).
// Batch-staged inner loop: lanes 0..n-1 load one entry index (coalesced
// ushort) + 48B face record (3x dwordx4, ONE vmcnt batch per chunk), stage to
// wave-private LDS, then the entry loop reads via same-address ds_read_b128
// (broadcast, conflict-free, compiler-pipelined). Wave-internal s_waitcnt
// lgkmcnt(0) orders write->read (no block barrier: trip counts differ).
// Pixel math expression-identical to all verified rounds; min3 predicate is
// an exact reformulation of the three sign tests. zb pre-read per pixel;
// atomicMin only when it would win (zb monotone-decreasing -> stale read
// conservatively safe).
__launch_bounds__(256)
__global__ void kraster(const float4* __restrict__ fd, const unsigned short* __restrict__ list,
                        const int* __restrict__ items, const int* __restrict__ misc,
                        unsigned int* __restrict__ zb) {
    __shared__ float4 sdata[4][CHK * 3];   // 6 KB: [wave][entry*3 + part]
    const int wslot = __builtin_amdgcn_readfirstlane(threadIdx.x >> 6);
    const int wid = blockIdx.x * 4 + wslot;
    const int lane = threadIdx.x & 63;
    const int cx = lane & 15;
    const int ry = lane >> 4;
    const int ni = __builtin_amdgcn_readfirstlane(misc[64]);
    float4* sd = &sdata[wslot][0];

    for (int it = wid; it < ni; it += RWAVES) {
        const int pk = __builtin_amdgcn_readfirstlane(items[it]);
        const int tile = pk >> 16;
        const int n = (pk >> 8) & 0xff;
        const int chunk = pk & 0xff;
        const int bx = tile & 15;
        const int by = tile >> 4;
        const int j = bx * 16 + cx;
        const float px = ((float)(2 * j + 1) - 256.0f) * (1.0f / 256.0f);
        float py[4];
        int row[4];
        unsigned int zcur[4];
#pragma unroll
        for (int r = 0; r < 4; ++r) {
            row[r] = by * 16 + ry + 4 * r;
            py[r] = ((float)(2 * row[r] + 1) - 256.0f) * (1.0f / 256.0f);
            zcur[r] = zb[row[r] * IS + j];
        }
        // ---- stage this chunk's face records into wave-private LDS ----
        const unsigned short* lp = list + (size_t)tile * CAP + chunk * CHK;
        if (lane < n) {
            const int fidx = lp[lane];                 // coalesced 2B/lane
            const float4* p = fd + (size_t)fidx * 4;   // 3 dwordx4, batched vmcnt
            float4 b0 = p[0];
            float4 b1 = p[1];
            float4 b2 = p[2];
            sd[lane * 3 + 0] = b0;
            sd[lane * 3 + 1] = b1;
            sd[lane * 3 + 2] = b2;
        }
        // wave-internal write->read ordering (no block barrier)
        asm volatile("s_waitcnt lgkmcnt(0)" ::: "memory");

        float mx[4] = {0.0f, 0.0f, 0.0f, 0.0f};

#pragma unroll 2
        for (int e = 0; e < n; ++e) {
            float4 a0 = sd[e * 3 + 0];   // uniform addr -> LDS broadcast
            float4 a1 = sd[e * 3 + 1];
            float4 a2 = sd[e * 3 + 2];
            float dx0 = a0.x - px, dx1 = a0.z - px, dx2 = a1.x - px;
#pragma unroll
            for (int r = 0; r < 4; ++r) {
                float dy0 = a0.y - py[r], dy1 = a0.w - py[r], dy2 = a1.y - py[r];
                float e0 = dx1 * dy2 - dx2 * dy1;
                float e1 = dx2 * dy0 - dx0 * dy2;
                float w0 = e0 * a1.z;
                float w1 = e1 * a1.z;
                float w2 = 1.0f - w0 - w1;
                float invz = w0 * a1.w + w1 * a2.x + w2 * a2.y;
                float invzc = fmaxf(invz, 1e-6f);
                // all(w>=0) <=> min3(w0,w1,w2)>=0 (exact; mult by positive ia
                // preserves sign). valid NEAR<zp<FAR <=> 0.01 < invzc < 10.
                float wmin = fminf(fminf(w0, w1), w2);
                bool ok = (wmin >= 0.0f) && (invzc < 10.0f) && (invzc > 0.01f);
                if (ok) mx[r] = fmaxf(mx[r], invzc);
            }
        }
#pragma unroll
        for (int r = 0; r < 4; ++r) {
            if (mx[r] > 0.0f) {
                float zp = 1.0f / mx[r];  // correctly-rounded 1/x monotone => min-exact
                unsigned int zbits = __float_as_uint(zp);
                if (zbits < zcur[r]) atomicMin(&zb[row[r] * IS + j], zbits);
            }
        }
    }
}

extern "C" void kernel_launch(void* const* d_in, const int* in_sizes, int n_in,
                              void* d_out, int out_size, void* d_ws, size_t ws_size,
                              hipStream_t stream) {
    const float* verts = (const float*)d_in[0];
    const int* faces = (const int*)d_in[1];
    unsigned int* zb = (unsigned int*)d_out;  // float bits, min'd in place

    const int nf = in_sizes[1] / 3;  // 5000 (< CAP and < 65536: ushort indices ok)

    char* ws = (char*)d_ws;
    size_t off = 0;
    float4* fd = (float4*)(ws + off);            off += (size_t)nf * 64;          // 320 KB
    off = (off + 255) & ~(size_t)255;
    int* count = (int*)(ws + off);               off += NTILES * 4;               // 1 KB
    int* misc = (int*)(ws + off);                off += 512;  // [0]=ticket, [64]=nitems
    int* items = (int*)(ws + off);               off += (size_t)MAXITEMS * 4;     // 160 KB
    off = (off + 255) & ~(size_t)255;
    unsigned short* list = (unsigned short*)(ws + off);  // 256*5120*2 = 2.62 MB

    const int nb = (nf + BTH - 1) / BTH;  // 5 blocks x 1024 threads

    // count (1KB) + misc (512B) are contiguous: one stream-ordered DMA clear
    hipMemsetAsync(count, 0, NTILES * 4 + 512, stream);
    kbinprep<<<nb, BTH, 0, stream>>>(verts, faces, fd, count, list, misc, items, zb, nf);
    kraster<<<RBLOCKS, 256, 0, stream>>>(fd, list, items, misc, zb);
}